// Round 1
// baseline (434.679 us; speedup 1.0000x reference)
//
#include <hip/hip_runtime.h>
#include <hip/hip_fp16.h>

typedef _Float16 f16;
typedef _Float16 f16x8 __attribute__((ext_vector_type(8)));
typedef float f32x4 __attribute__((ext_vector_type(4)));

#define HDIM 256
#define TSTEPS 128
#define OUTDIM 10

// Block: 256 threads = 4 waves. Each block owns 16 batch rows.
// Transposed recurrence: Y[n][m] = sum_k W[n][k] * a[m][k]
//   MFMA A-operand = W slice (wave w owns n in [w*64, w*64+64)), static in VGPRs.
//   MFMA B-operand = a (lane col = batch), repacked each step from acc (D layout
//   == next B layout under our k-convention k = q*4 + (j&3) + 16*(j>>2) + 32c).
__global__ __launch_bounds__(256, 2) void rnn_kernel(
    const float* __restrict__ x,         // [B, T]
    const float* __restrict__ embed_w,   // [256]
    const float* __restrict__ embed_b,   // [256]
    const float* __restrict__ update_w,  // [256,256] row-major [n][k]
    const float* __restrict__ update_b,  // [256]
    const float* __restrict__ gamma,     // [256]
    const float* __restrict__ beta,      // [256]
    const float* __restrict__ out_w,     // [10,256]
    const float* __restrict__ out_b,     // [10]
    float* __restrict__ out)             // [B,10]
{
  __shared__ __align__(16) f16  sTBL[8][4][10][8];   // inp table, frag-element order
  __shared__ __align__(16) float sUB0[HDIM];          // update_b
  __shared__ __align__(16) float sUB1[HDIM];          // update_b + beta@W^T
  __shared__ __align__(16) f16  sFrag[8][64][8];      // b-frag exchange
  __shared__ float sStats[4][16][2];
  __shared__ float sOut[4][16][OUTDIM];

  const int tid = threadIdx.x;
  const int w  = tid >> 6;      // wave 0..3
  const int l  = tid & 63;      // lane
  const int q  = l >> 4;        // quarter-group 0..3
  const int ml = l & 15;        // batch col within tile
  const int base = blockIdx.x * 16;

  // ---- one-time init: inp table (x values are integers 0..9) ----
  for (int e = tid; e < 2560; e += 256) {
    int j  = e & 7;
    int r1 = e >> 3;
    int xv = r1 % 10;
    int r2 = r1 / 10;           // = c*4 + q2
    int q2 = r2 & 3;
    int c  = r2 >> 2;
    int k  = c * 32 + q2 * 4 + (j & 3) + 16 * (j >> 2);
    float v = tanhf((float)xv * embed_w[k] + embed_b[k]);
    sTBL[c][q2][xv][j] = (f16)v;
  }
  // ---- biases: ub0 = update_b ; ub1 = update_b + beta @ W^T ----
  {
    int n = tid;                 // 256 threads, one n each
    float u = update_b[n];
    sUB0[n] = u;
    float a = 0.f;
    const float* wr = update_w + n * HDIM;
    for (int k2 = 0; k2 < HDIM; k2 += 4) {
      float4 wb = *(const float4*)(wr + k2);
      float4 bb = *(const float4*)(beta + k2);
      a += wb.x * bb.x + wb.y * bb.y + wb.z * bb.z + wb.w * bb.w;
    }
    sUB1[n] = u + a;
  }

  // ---- W fragments (A operand) into registers: 128 VGPRs ----
  f16x8 wf[4][8];
  #pragma unroll
  for (int nt = 0; nt < 4; nt++) {
    const int n = w * 64 + nt * 16 + ml;
    const float* wr = update_w + n * HDIM;
    #pragma unroll
    for (int c = 0; c < 8; c++) {
      const int k0 = c * 32 + q * 4;
      float4 a0 = *(const float4*)(wr + k0);
      float4 a1 = *(const float4*)(wr + k0 + 16);
      f16x8 f;
      f[0] = (f16)a0.x; f[1] = (f16)a0.y; f[2] = (f16)a0.z; f[3] = (f16)a0.w;
      f[4] = (f16)a1.x; f[5] = (f16)a1.y; f[6] = (f16)a1.z; f[7] = (f16)a1.w;
      wf[nt][c] = f;
    }
  }
  // ---- gamma values for this wave's own pack chunks ----
  float gk[2][8];
  #pragma unroll
  for (int cc = 0; cc < 2; cc++) {
    const int c = w * 2 + cc;
    const int k0 = c * 32 + q * 4;
    float4 g0 = *(const float4*)(gamma + k0);
    float4 g1 = *(const float4*)(gamma + k0 + 16);
    gk[cc][0] = g0.x; gk[cc][1] = g0.y; gk[cc][2] = g0.z; gk[cc][3] = g0.w;
    gk[cc][4] = g1.x; gk[cc][5] = g1.y; gk[cc][6] = g1.z; gk[cc][7] = g1.w;
  }
  __syncthreads();

  // ---- t=0 fragments: a_0 = inp_0 (h=0, no beta) ----
  const float* xrow = x + (size_t)(base + ml) * TSTEPS;
  {
    int xv0 = (int)xrow[0];
    (void)xv0;
  }
  f16x8 bf[8];
  {
    const int xv0 = (int)xrow[0];
    #pragma unroll
    for (int c = 0; c < 8; c++)
      bf[c] = *(const f16x8*)(&sTBL[c][q][xv0][0]);
  }

  f32x4 acc[4];
  float mu = 0.f, rs = 1.f;

  for (int t = 0; t < TSTEPS; t++) {
    // prefetch next-step x early (hides L1/L2 latency under MFMA)
    float xnf = 0.f;
    if (t < TSTEPS - 1) xnf = xrow[t + 1];

    const float* ub = (t == 0) ? sUB0 : sUB1;
    f32x4 ubv[4];
    #pragma unroll
    for (int nt = 0; nt < 4; nt++)
      ubv[nt] = *(const f32x4*)(ub + w * 64 + nt * 16 + q * 4);

    #pragma unroll
    for (int nt = 0; nt < 4; nt++) acc[nt] = (f32x4){0.f, 0.f, 0.f, 0.f};

    #pragma unroll
    for (int c = 0; c < 8; c++) {
      #pragma unroll
      for (int nt = 0; nt < 4; nt++)
        acc[nt] = __builtin_amdgcn_mfma_f32_16x16x32_f16(wf[nt][c], bf[c], acc[nt], 0, 0, 0);
    }

    // tanh(y + ub) in place; LN partial sums
    float s1 = 0.f, s2 = 0.f;
    #pragma unroll
    for (int nt = 0; nt < 4; nt++) {
      #pragma unroll
      for (int r = 0; r < 4; r++) {
        float v  = acc[nt][r] + ubv[nt][r];
        float e2 = __builtin_amdgcn_exp2f(v * 2.8853900817779268f);  // exp(2v)
        float tv = 1.f - 2.f * __builtin_amdgcn_rcpf(e2 + 1.f);
        acc[nt][r] = tv;
        s1 += tv;
        s2 += tv * tv;
      }
    }
    // reduce over the 4 lanes sharing this batch col (within wave)
    s1 += __shfl_xor(s1, 16, 64);  s2 += __shfl_xor(s2, 16, 64);
    s1 += __shfl_xor(s1, 32, 64);  s2 += __shfl_xor(s2, 32, 64);
    if (l < 16) { sStats[w][ml][0] = s1; sStats[w][ml][1] = s2; }
    __syncthreads();   // barrier 1: stats ready (also fences sFrag reads of t-1)
    float S1 = sStats[0][ml][0] + sStats[1][ml][0] + sStats[2][ml][0] + sStats[3][ml][0];
    float S2 = sStats[0][ml][1] + sStats[1][ml][1] + sStats[2][ml][1] + sStats[3][ml][1];
    mu = S1 * (1.f / 256.f);
    float var = S2 * (1.f / 256.f) - mu * mu;
    rs = __frsqrt_rn(var + 1e-5f);

    if (t < TSTEPS - 1) {
      const int xn = (int)xnf;
      // pack this wave's own 2 chunks: a = inp_{t+1} + z*gamma  (beta folded into ub1)
      #pragma unroll
      for (int cc = 0; cc < 2; cc++) {
        const int c = w * 2 + cc;
        f16x8 tb = *(const f16x8*)(&sTBL[c][q][xn][0]);
        f16x8 af;
        #pragma unroll
        for (int j = 0; j < 8; j++) {
          float z = (acc[2 * cc + (j >> 2)][j & 3] - mu) * rs;
          af[j] = (f16)((float)tb[j] + z * gk[cc][j]);
        }
        *(f16x8*)(&sFrag[c][l][0]) = af;
      }
      __syncthreads(); // barrier 2: fragments ready
      #pragma unroll
      for (int c = 0; c < 8; c++)
        bf[c] = *(const f16x8*)(&sFrag[c][l][0]);
    }
  }

  // ---- final projection: out = (z*gamma) @ out_w^T + (out_b + beta @ out_w^T) ----
  float hz[4][4];
  #pragma unroll
  for (int nt = 0; nt < 4; nt++) {
    const int n0 = w * 64 + nt * 16 + q * 4;
    float4 g = *(const float4*)(gamma + n0);
    hz[nt][0] = (acc[nt][0] - mu) * rs * g.x;
    hz[nt][1] = (acc[nt][1] - mu) * rs * g.y;
    hz[nt][2] = (acc[nt][2] - mu) * rs * g.z;
    hz[nt][3] = (acc[nt][3] - mu) * rs * g.w;
  }
  float p[OUTDIM];
  #pragma unroll
  for (int o = 0; o < OUTDIM; o++) {
    const float* owr = out_w + o * HDIM + w * 64;
    float s = 0.f;
    #pragma unroll
    for (int nt = 0; nt < 4; nt++) {
      float4 ov = *(const float4*)(owr + nt * 16 + q * 4);
      s += hz[nt][0] * ov.x + hz[nt][1] * ov.y + hz[nt][2] * ov.z + hz[nt][3] * ov.w;
    }
    s += __shfl_xor(s, 16, 64);
    s += __shfl_xor(s, 32, 64);
    p[o] = s;
  }
  if (l < 16) {
    #pragma unroll
    for (int o = 0; o < OUTDIM; o++) sOut[w][ml][o] = p[o];
  }
  __syncthreads();
  if (tid < 16 * OUTDIM) {
    const int m = tid / OUTDIM;
    const int o = tid % OUTDIM;
    float s = sOut[0][m][o] + sOut[1][m][o] + sOut[2][m][o] + sOut[3][m][o];
    // fold beta @ out_w^T into the bias
    float bacc = 0.f;
    const float* owr = out_w + o * HDIM;
    for (int k2 = 0; k2 < HDIM; k2 += 4) {
      float4 wv = *(const float4*)(owr + k2);
      float4 bv = *(const float4*)(beta + k2);
      bacc += wv.x * bv.x + wv.y * bv.y + wv.z * bv.z + wv.w * bv.w;
    }
    out[(size_t)(base + m) * OUTDIM + o] = s + out_b[o] + bacc;
  }
}

extern "C" void kernel_launch(void* const* d_in, const int* in_sizes, int n_in,
                              void* d_out, int out_size, void* d_ws, size_t ws_size,
                              hipStream_t stream) {
  const float* x   = (const float*)d_in[0];
  const float* ew  = (const float*)d_in[1];
  const float* eb  = (const float*)d_in[2];
  const float* uw  = (const float*)d_in[3];
  const float* ub  = (const float*)d_in[4];
  const float* g   = (const float*)d_in[5];
  const float* be  = (const float*)d_in[6];
  const float* ow  = (const float*)d_in[7];
  const float* ob  = (const float*)d_in[8];
  float* out = (float*)d_out;

  const int B = in_sizes[0] / TSTEPS;   // 16384
  const int grid = B / 16;              // 1024 blocks
  hipLaunchKernelGGL(rnn_kernel, dim3(grid), dim3(256), 0, stream,
                     x, ew, eb, uw, ub, g, be, ow, ob, out);
}